// Round 2
// baseline (56.035 us; speedup 1.0000x reference)
//
#include <hip/hip_runtime.h>

// PosFeatureLayer: out[b,m,d] = emb[b,m,d] + (m < num[b] ? feat(pts[b, idx[b,m]]) . W[:,d] : 0)
// feat = [(x-cx)/s, (y-cy)/s, (ang-45)/126, (len-lscale/2)/lscale]
// Pure streaming op: read emb (134MB) + write out (134MB); gathers are L2-resident.
// NOTE: harness passes ALL integer inputs as int32 (incl. image_shape).

__global__ __launch_bounds__(256) void PosFeatureLayer_83416854823346_kernel(
    const float* __restrict__ emb,            // [B,M,D]
    const int* __restrict__ num,              // [B]
    const float* __restrict__ pts,            // [B,N,5]
    const int* __restrict__ indeces,          // [B,M]
    const int* __restrict__ image_shape,      // [4] int32: (b, c, H, W)
    const float* __restrict__ W,              // [4,D]
    float* __restrict__ out,                  // [B,M,D]
    int B, int M, int N, int D)
{
    const int lane = threadIdx.x & 63;
    const int wave = threadIdx.x >> 6;                 // 4 waves per block
    const int m = blockIdx.x * 4 + wave;               // one wave per output row
    const int b = blockIdx.y;
    if (m >= M) return;

    // Scalars from image_shape (wave-uniform, cached)
    const float h = (float)image_shape[2];
    const float w = (float)image_shape[3];
    const float scaling = fmaxf(w, h) * 0.7f;
    const float inv_s   = 1.0f / scaling;
    const float cx = w * 0.5f, cy = h * 0.5f;
    const float lscale = sqrtf(w * w + h * h) * 0.7f;
    const float inv_l  = 1.0f / lscale;
    const float inv_a  = 1.0f / (180.0f * 0.7f);

    // Row-level feature (wave-uniform; zero when masked -> branch-free add)
    float f0 = 0.f, f1 = 0.f, f2 = 0.f, f3 = 0.f;
    if (m < num[b]) {
        const int idx = indeces[(long long)b * M + m];
        const float* p = pts + ((long long)b * N + (long long)idx) * 5;
        f0 = (p[0] - cx) * inv_s;
        f1 = (p[1] - cy) * inv_s;
        f2 = (p[4] - 45.0f) * inv_a;
        f3 = (p[3] - lscale * 0.5f) * inv_l;
    }

    const long long rowoff = ((long long)b * M + m) * (long long)D;
    // 64 lanes x float4 covers D=256 in one step; loop form stays correct for larger D.
    for (int d0 = lane * 4; d0 < D; d0 += 64 * 4) {
        const float4 w0 = *(const float4*)(W + 0 * D + d0);
        const float4 w1 = *(const float4*)(W + 1 * D + d0);
        const float4 w2 = *(const float4*)(W + 2 * D + d0);
        const float4 w3 = *(const float4*)(W + 3 * D + d0);
        const float4 e  = *(const float4*)(emb + rowoff + d0);
        float4 r;
        r.x = e.x + f0 * w0.x + f1 * w1.x + f2 * w2.x + f3 * w3.x;
        r.y = e.y + f0 * w0.y + f1 * w1.y + f2 * w2.y + f3 * w3.y;
        r.z = e.z + f0 * w0.z + f1 * w1.z + f2 * w2.z + f3 * w3.z;
        r.w = e.w + f0 * w0.w + f1 * w1.w + f2 * w2.w + f3 * w3.w;
        *(float4*)(out + rowoff + d0) = r;
    }
}

extern "C" void kernel_launch(void* const* d_in, const int* in_sizes, int n_in,
                              void* d_out, int out_size, void* d_ws, size_t ws_size,
                              hipStream_t stream) {
    (void)n_in; (void)d_ws; (void)ws_size;
    const float* emb  = (const float*)d_in[0];
    const int*   num  = (const int*)d_in[1];
    const float* pts  = (const float*)d_in[2];
    const int*   idx  = (const int*)d_in[3];
    const int*   ishp = (const int*)d_in[4];
    const float* Wm   = (const float*)d_in[5];
    float*       out  = (float*)d_out;

    const int B = in_sizes[1];                       // num: [B]
    const int D = in_sizes[5] / 4;                   // W: [4,D]
    const int M = (int)((long long)in_sizes[3] / B); // indeces: [B,M]
    const int N = (int)((long long)in_sizes[2] / ((long long)B * 5)); // pts: [B,N,5]
    (void)out_size;

    dim3 block(256);
    dim3 grid((M + 3) / 4, B);
    hipLaunchKernelGGL(PosFeatureLayer_83416854823346_kernel, grid, block, 0, stream,
                       emb, num, pts, idx, ishp, Wm, out, B, M, N, D);
}

// Round 3
// 48.117 us; speedup vs baseline: 1.1646x; 1.1646x over previous
//
#include <hip/hip_runtime.h>

// PosFeatureLayer: out[b,m,d] = emb[b,m,d] + (m < num[b] ? feat(pts[b, idx[b,m]]) . W[:,d] : 0)
// Streaming op. Round-2 structure: 8 rows/wave, W in regs, lane-parallel
// idx/pts gather + shfl broadcast, 8-deep emb-load pipeline.

#define DD 256  // fast path: D == 256 (64 lanes x float4)

__global__ __launch_bounds__(256) void posfeat_d256_kernel(
    const float* __restrict__ emb,            // [B,M,DD]
    const int* __restrict__ num,              // [B]
    const float* __restrict__ pts,            // [B,N,5]
    const int* __restrict__ indeces,          // [B,M]
    const int* __restrict__ image_shape,      // [4] int32 (b,c,H,W)
    const float* __restrict__ W,              // [4,DD]
    float* __restrict__ out,                  // [B,M,DD]
    int B, int M, int N)
{
    const int lane = threadIdx.x & 63;
    const int wave = threadIdx.x >> 6;                  // 4 waves/block
    const int b = blockIdx.y;
    const int base_m = (blockIdx.x * 4 + wave) * 8;     // 8 rows per wave
    if (base_m >= M) return;

    const float h = (float)image_shape[2];
    const float w = (float)image_shape[3];
    const float inv_s  = 1.0f / (fmaxf(w, h) * 0.7f);
    const float cx = w * 0.5f, cy = h * 0.5f;
    const float lscale = sqrtf(w * w + h * h) * 0.7f;
    const float inv_l  = 1.0f / lscale;
    const float half_l = lscale * 0.5f;
    const float inv_a  = 1.0f / 126.0f;

    // W fragment in registers, loaded once per wave (L1-hit)
    const int d0 = lane * 4;
    const float4 w0 = *(const float4*)(W + 0 * DD + d0);
    const float4 w1 = *(const float4*)(W + 1 * DD + d0);
    const float4 w2 = *(const float4*)(W + 2 * DD + d0);
    const float4 w3 = *(const float4*)(W + 3 * DD + d0);

    const int nb = num[b];

    // lanes 0..7: gather the 8 row indices (masked rows -> -1)
    int idxv = -1;
    if (lane < 8) {
        const int m = base_m + lane;
        if (m < M && m < nb) idxv = indeces[(long long)b * M + m];
    }
    // lanes 0..39: gather pts scalars in parallel (row = lane/5, comp = lane%5)
    float pv = 0.f;
    {
        const int r = lane / 5, c = lane - r * 5;
        const int ir = __shfl(idxv, r);
        if (lane < 40 && ir >= 0)
            pv = pts[((long long)b * N + ir) * 5 + c];
    }

    const long long baseoff = ((long long)b * M + base_m) * DD + d0;
    const int nrows = (M - base_m < 8) ? (M - base_m) : 8;

    // Issue all emb loads first (independent -> deep MLP)
    float4 e[8];
    #pragma unroll
    for (int r = 0; r < 8; ++r)
        if (r < nrows) e[r] = *(const float4*)(emb + baseoff + (long long)r * DD);

    #pragma unroll
    for (int r = 0; r < 8; ++r) {
        if (r >= nrows) continue;
        const int   ir = __shfl(idxv, r);
        const float p0 = __shfl(pv, r * 5 + 0);
        const float p1 = __shfl(pv, r * 5 + 1);
        const float p3 = __shfl(pv, r * 5 + 3);
        const float p4 = __shfl(pv, r * 5 + 4);
        float f0 = 0.f, f1 = 0.f, f2 = 0.f, f3 = 0.f;
        if (ir >= 0) {
            f0 = (p0 - cx) * inv_s;
            f1 = (p1 - cy) * inv_s;
            f2 = (p4 - 45.0f) * inv_a;
            f3 = (p3 - half_l) * inv_l;
        }
        float4 o;
        o.x = e[r].x + f0 * w0.x + f1 * w1.x + f2 * w2.x + f3 * w3.x;
        o.y = e[r].y + f0 * w0.y + f1 * w1.y + f2 * w2.y + f3 * w3.y;
        o.z = e[r].z + f0 * w0.z + f1 * w1.z + f2 * w2.z + f3 * w3.z;
        o.w = e[r].w + f0 * w0.w + f1 * w1.w + f2 * w2.w + f3 * w3.w;
        *(float4*)(out + baseoff + (long long)r * DD) = o;
    }
}

// Generic fallback (any D multiple of 4): round-1 structure, 1 row/wave.
__global__ __launch_bounds__(256) void posfeat_generic_kernel(
    const float* __restrict__ emb, const int* __restrict__ num,
    const float* __restrict__ pts, const int* __restrict__ indeces,
    const int* __restrict__ image_shape, const float* __restrict__ W,
    float* __restrict__ out, int B, int M, int N, int D)
{
    const int lane = threadIdx.x & 63;
    const int wave = threadIdx.x >> 6;
    const int m = blockIdx.x * 4 + wave;
    const int b = blockIdx.y;
    if (m >= M) return;
    const float h = (float)image_shape[2];
    const float w = (float)image_shape[3];
    const float inv_s = 1.0f / (fmaxf(w, h) * 0.7f);
    const float cx = w * 0.5f, cy = h * 0.5f;
    const float lscale = sqrtf(w * w + h * h) * 0.7f;
    const float inv_l = 1.0f / lscale;
    const float inv_a = 1.0f / 126.0f;
    float f0 = 0.f, f1 = 0.f, f2 = 0.f, f3 = 0.f;
    if (m < num[b]) {
        const int idx = indeces[(long long)b * M + m];
        const float* p = pts + ((long long)b * N + (long long)idx) * 5;
        f0 = (p[0] - cx) * inv_s;
        f1 = (p[1] - cy) * inv_s;
        f2 = (p[4] - 45.0f) * inv_a;
        f3 = (p[3] - lscale * 0.5f) * inv_l;
    }
    const long long rowoff = ((long long)b * M + m) * (long long)D;
    for (int dd = lane * 4; dd < D; dd += 64 * 4) {
        const float4 w0 = *(const float4*)(W + 0 * D + dd);
        const float4 w1 = *(const float4*)(W + 1 * D + dd);
        const float4 w2 = *(const float4*)(W + 2 * D + dd);
        const float4 w3 = *(const float4*)(W + 3 * D + dd);
        const float4 e  = *(const float4*)(emb + rowoff + dd);
        float4 r;
        r.x = e.x + f0 * w0.x + f1 * w1.x + f2 * w2.x + f3 * w3.x;
        r.y = e.y + f0 * w0.y + f1 * w1.y + f2 * w2.y + f3 * w3.y;
        r.z = e.z + f0 * w0.z + f1 * w1.z + f2 * w2.z + f3 * w3.z;
        r.w = e.w + f0 * w0.w + f1 * w1.w + f2 * w2.w + f3 * w3.w;
        *(float4*)(out + rowoff + dd) = r;
    }
}

extern "C" void kernel_launch(void* const* d_in, const int* in_sizes, int n_in,
                              void* d_out, int out_size, void* d_ws, size_t ws_size,
                              hipStream_t stream) {
    (void)n_in; (void)d_ws; (void)ws_size; (void)out_size;
    const float* emb  = (const float*)d_in[0];
    const int*   num  = (const int*)d_in[1];
    const float* pts  = (const float*)d_in[2];
    const int*   idx  = (const int*)d_in[3];
    const int*   ishp = (const int*)d_in[4];
    const float* Wm   = (const float*)d_in[5];
    float*       out  = (float*)d_out;

    const int B = in_sizes[1];
    const int D = in_sizes[5] / 4;
    const int M = (int)((long long)in_sizes[3] / B);
    const int N = (int)((long long)in_sizes[2] / ((long long)B * 5));

    if (D == 256) {
        dim3 block(256);
        dim3 grid((M + 31) / 32, B);   // 4 waves/block x 8 rows/wave
        hipLaunchKernelGGL(posfeat_d256_kernel, grid, block, 0, stream,
                           emb, num, pts, idx, ishp, Wm, out, B, M, N);
    } else {
        dim3 block(256);
        dim3 grid((M + 3) / 4, B);
        hipLaunchKernelGGL(posfeat_generic_kernel, grid, block, 0, stream,
                           emb, num, pts, idx, ishp, Wm, out, B, M, N, D);
    }
}

// Round 5
// 46.788 us; speedup vs baseline: 1.1976x; 1.0284x over previous
//
#include <hip/hip_runtime.h>

// PosFeatureLayer: out[b,m,d] = emb[b,m,d] + (m < num[b] ? feat(pts[b, idx[b,m]]) . W[:,d] : 0)
// Round-4: same as Round-3 (grid-stride persistent waves, 8 rows/tile,
// non-temporal out-stores) with native ext_vector_type for the nt builtin.

typedef float f32x4 __attribute__((ext_vector_type(4)));

#define DD 256  // fast path: D == 256 (64 lanes x f32x4)

__global__ __launch_bounds__(256) void posfeat_d256_kernel(
    const float* __restrict__ emb,            // [B,M,DD]
    const int* __restrict__ num,              // [B]
    const float* __restrict__ pts,            // [B,N,5]
    const int* __restrict__ indeces,          // [B,M]
    const int* __restrict__ image_shape,      // [4] int32 (b,c,H,W)
    const float* __restrict__ W,              // [4,DD]
    float* __restrict__ out,                  // [B,M,DD]
    int B, int M, int N, int tiles_per_b, int total_tiles)
{
    const int lane = threadIdx.x & 63;
    const int wave = threadIdx.x >> 6;                  // 4 waves/block
    const int waves_per_grid = gridDim.x * 4;

    const float h = (float)image_shape[2];
    const float w = (float)image_shape[3];
    const float inv_s  = 1.0f / (fmaxf(w, h) * 0.7f);
    const float cx = w * 0.5f, cy = h * 0.5f;
    const float lscale = sqrtf(w * w + h * h) * 0.7f;
    const float inv_l  = 1.0f / lscale;
    const float half_l = lscale * 0.5f;
    const float inv_a  = 1.0f / 126.0f;

    // W fragment in registers, loaded once per wave (L1-hit)
    const int d0 = lane * 4;
    const f32x4 w0 = *(const f32x4*)(W + 0 * DD + d0);
    const f32x4 w1 = *(const f32x4*)(W + 1 * DD + d0);
    const f32x4 w2 = *(const f32x4*)(W + 2 * DD + d0);
    const f32x4 w3 = *(const f32x4*)(W + 3 * DD + d0);

    const int pr = lane / 5, pc = lane - pr * 5;        // pts-gather role of this lane

    for (int tile = blockIdx.x * 4 + wave; tile < total_tiles; tile += waves_per_grid) {
        const int b      = tile / tiles_per_b;
        const int base_m = (tile - b * tiles_per_b) * 8;
        const int nb     = num[b];

        // lanes 0..7: gather the 8 row indices (masked rows -> -1)
        int idxv = -1;
        if (lane < 8) {
            const int m = base_m + lane;
            if (m < M && m < nb) idxv = indeces[(long long)b * M + m];
        }
        // lanes 0..39: gather pts scalars in parallel (row = lane/5, comp = lane%5)
        const int ir_g = __shfl(idxv, pr);
        float pv = 0.f;
        if (lane < 40 && ir_g >= 0)
            pv = pts[((long long)b * N + ir_g) * 5 + pc];

        const long long baseoff = ((long long)b * M + base_m) * DD + d0;
        const int nrows = (M - base_m < 8) ? (M - base_m) : 8;

        // Issue all emb loads first (independent -> deep memory-level parallelism)
        f32x4 e[8];
        #pragma unroll
        for (int r = 0; r < 8; ++r)
            if (r < nrows) e[r] = *(const f32x4*)(emb + baseoff + (long long)r * DD);

        #pragma unroll
        for (int r = 0; r < 8; ++r) {
            if (r >= nrows) continue;
            const int   ir = __shfl(idxv, r);
            const float p0 = __shfl(pv, r * 5 + 0);
            const float p1 = __shfl(pv, r * 5 + 1);
            const float p3 = __shfl(pv, r * 5 + 3);
            const float p4 = __shfl(pv, r * 5 + 4);
            float f0 = 0.f, f1 = 0.f, f2 = 0.f, f3 = 0.f;
            if (ir >= 0) {
                f0 = (p0 - cx) * inv_s;
                f1 = (p1 - cy) * inv_s;
                f2 = (p4 - 45.0f) * inv_a;
                f3 = (p3 - half_l) * inv_l;
            }
            f32x4 o;
            o.x = e[r].x + f0 * w0.x + f1 * w1.x + f2 * w2.x + f3 * w3.x;
            o.y = e[r].y + f0 * w0.y + f1 * w1.y + f2 * w2.y + f3 * w3.y;
            o.z = e[r].z + f0 * w0.z + f1 * w1.z + f2 * w2.z + f3 * w3.z;
            o.w = e[r].w + f0 * w0.w + f1 * w1.w + f2 * w2.w + f3 * w3.w;
            // Non-temporal: out is write-once, never re-read -> don't pollute L2/L3.
            __builtin_nontemporal_store(o, (f32x4*)(out + baseoff + (long long)r * DD));
        }
    }
}

// Generic fallback (any D multiple of 4): 1 row/wave.
__global__ __launch_bounds__(256) void posfeat_generic_kernel(
    const float* __restrict__ emb, const int* __restrict__ num,
    const float* __restrict__ pts, const int* __restrict__ indeces,
    const int* __restrict__ image_shape, const float* __restrict__ W,
    float* __restrict__ out, int B, int M, int N, int D)
{
    const int lane = threadIdx.x & 63;
    const int wave = threadIdx.x >> 6;
    const int m = blockIdx.x * 4 + wave;
    const int b = blockIdx.y;
    if (m >= M) return;
    const float h = (float)image_shape[2];
    const float w = (float)image_shape[3];
    const float inv_s = 1.0f / (fmaxf(w, h) * 0.7f);
    const float cx = w * 0.5f, cy = h * 0.5f;
    const float lscale = sqrtf(w * w + h * h) * 0.7f;
    const float inv_l = 1.0f / lscale;
    const float inv_a = 1.0f / 126.0f;
    float f0 = 0.f, f1 = 0.f, f2 = 0.f, f3 = 0.f;
    if (m < num[b]) {
        const int idx = indeces[(long long)b * M + m];
        const float* p = pts + ((long long)b * N + (long long)idx) * 5;
        f0 = (p[0] - cx) * inv_s;
        f1 = (p[1] - cy) * inv_s;
        f2 = (p[4] - 45.0f) * inv_a;
        f3 = (p[3] - lscale * 0.5f) * inv_l;
    }
    const long long rowoff = ((long long)b * M + m) * (long long)D;
    for (int dd = lane * 4; dd < D; dd += 64 * 4) {
        const f32x4 w0 = *(const f32x4*)(W + 0 * D + dd);
        const f32x4 w1 = *(const f32x4*)(W + 1 * D + dd);
        const f32x4 w2 = *(const f32x4*)(W + 2 * D + dd);
        const f32x4 w3 = *(const f32x4*)(W + 3 * D + dd);
        const f32x4 e  = *(const f32x4*)(emb + rowoff + dd);
        f32x4 r;
        r.x = e.x + f0 * w0.x + f1 * w1.x + f2 * w2.x + f3 * w3.x;
        r.y = e.y + f0 * w0.y + f1 * w1.y + f2 * w2.y + f3 * w3.y;
        r.z = e.z + f0 * w0.z + f1 * w1.z + f2 * w2.z + f3 * w3.z;
        r.w = e.w + f0 * w0.w + f1 * w1.w + f2 * w2.w + f3 * w3.w;
        *(f32x4*)(out + rowoff + dd) = r;
    }
}

extern "C" void kernel_launch(void* const* d_in, const int* in_sizes, int n_in,
                              void* d_out, int out_size, void* d_ws, size_t ws_size,
                              hipStream_t stream) {
    (void)n_in; (void)d_ws; (void)ws_size; (void)out_size;
    const float* emb  = (const float*)d_in[0];
    const int*   num  = (const int*)d_in[1];
    const float* pts  = (const float*)d_in[2];
    const int*   idx  = (const int*)d_in[3];
    const int*   ishp = (const int*)d_in[4];
    const float* Wm   = (const float*)d_in[5];
    float*       out  = (float*)d_out;

    const int B = in_sizes[1];
    const int D = in_sizes[5] / 4;
    const int M = (int)((long long)in_sizes[3] / B);
    const int N = (int)((long long)in_sizes[2] / ((long long)B * 5));

    if (D == 256) {
        const int tiles_per_b = (M + 7) / 8;
        const int total_tiles = B * tiles_per_b;
        int blocks = (total_tiles + 3) / 4;
        if (blocks > 2048) blocks = 2048;     // 8 blocks/CU x 256 CU; grid-stride the rest
        hipLaunchKernelGGL(posfeat_d256_kernel, dim3(blocks), dim3(256), 0, stream,
                           emb, num, pts, idx, ishp, Wm, out, B, M, N,
                           tiles_per_b, total_tiles);
    } else {
        dim3 block(256);
        dim3 grid((M + 3) / 4, B);
        hipLaunchKernelGGL(posfeat_generic_kernel, grid, block, 0, stream,
                           emb, num, pts, idx, ishp, Wm, out, B, M, N, D);
    }
}

// Round 6
// 46.066 us; speedup vs baseline: 1.2164x; 1.0157x over previous
//
#include <hip/hip_runtime.h>

// PosFeatureLayer: out[b,m,d] = emb[b,m,d] + (m < num[b] ? feat(pts[b, idx[b,m]]) . W[:,d] : 0)
// Round-5: software-pipelined gather (prefetch tile t+1's idx/pts while tile t's
// emb loads are in flight), 2D grid (y=batch, no div), M%8==0 fast path.

typedef float f32x4 __attribute__((ext_vector_type(4)));

#define DD 256  // fast path: D == 256 (64 lanes x f32x4)

__global__ __launch_bounds__(256) void posfeat_d256_kernel(
    const float* __restrict__ emb,            // [B,M,DD]
    const int* __restrict__ num,              // [B]
    const float* __restrict__ pts,            // [B,N,5]
    const int* __restrict__ indeces,          // [B,M]
    const int* __restrict__ image_shape,      // [4] int32 (b,c,H,W)
    const float* __restrict__ W,              // [4,DD]
    float* __restrict__ out,                  // [B,M,DD]
    int M, int N, int tiles_per_b)
{
    const int lane = threadIdx.x & 63;
    const int wave = threadIdx.x >> 6;                  // 4 waves/block
    const int b = blockIdx.y;
    const int wv = blockIdx.x * 4 + wave;               // wave id within batch
    const int stride = gridDim.x * 4;

    const float h = (float)image_shape[2];
    const float w = (float)image_shape[3];
    const float inv_s  = 1.0f / (fmaxf(w, h) * 0.7f);
    const float cx = w * 0.5f, cy = h * 0.5f;
    const float lscale = sqrtf(w * w + h * h) * 0.7f;
    const float inv_l  = 1.0f / lscale;
    const float half_l = lscale * 0.5f;
    const float inv_a  = 1.0f / 126.0f;

    // W fragment in registers, loaded once per wave (L1-hit)
    const int d0 = lane * 4;
    const f32x4 w0 = *(const f32x4*)(W + 0 * DD + d0);
    const f32x4 w1 = *(const f32x4*)(W + 1 * DD + d0);
    const f32x4 w2 = *(const f32x4*)(W + 2 * DD + d0);
    const f32x4 w3 = *(const f32x4*)(W + 3 * DD + d0);

    const int pr = lane / 5, pc = lane - pr * 5;        // pts-gather role
    const int nb = num[b];
    const long long embb = (long long)b * M;            // row base for this batch
    const long long ptsb = (long long)b * N;

    // Gather idx (lanes 0..7) and pts scalars (lanes 0..39) for one tile.
    auto gather = [&](int tile, int& idxv, float& pv) {
        idxv = -1;
        if (lane < 8) {
            const int m = tile * 8 + lane;              // m < M guaranteed (M%8==0)
            if (m < nb) idxv = indeces[embb + m];
        }
        const int ir = __shfl(idxv, pr);
        pv = 0.f;
        if (lane < 40 && ir >= 0)
            pv = pts[(ptsb + ir) * 5 + pc];
    };

    int tile = wv;
    int idx0 = -1; float pv0 = 0.f;
    if (tile < tiles_per_b) gather(tile, idx0, pv0);

    for (; tile < tiles_per_b; tile += stride) {
        const long long baseoff = (embb + (long long)tile * 8) * DD + d0;

        // Issue current tile's emb loads (8 independent dwordx4 -> deep MLP)
        f32x4 e[8];
        #pragma unroll
        for (int r = 0; r < 8; ++r)
            e[r] = *(const f32x4*)(emb + baseoff + (long long)r * DD);

        // Prefetch NEXT tile's gather chain while emb loads are in flight
        const int tile2 = tile + stride;
        int idx1 = -1; float pv1 = 0.f;
        if (tile2 < tiles_per_b) gather(tile2, idx1, pv1);

        // Compute + store current tile from the already-resolved gather
        #pragma unroll
        for (int r = 0; r < 8; ++r) {
            const int   ir = __shfl(idx0, r);
            const float p0 = __shfl(pv0, r * 5 + 0);
            const float p1 = __shfl(pv0, r * 5 + 1);
            const float p3 = __shfl(pv0, r * 5 + 3);
            const float p4 = __shfl(pv0, r * 5 + 4);
            float f0 = 0.f, f1 = 0.f, f2 = 0.f, f3 = 0.f;
            if (ir >= 0) {
                f0 = (p0 - cx) * inv_s;
                f1 = (p1 - cy) * inv_s;
                f2 = (p4 - 45.0f) * inv_a;
                f3 = (p3 - half_l) * inv_l;
            }
            f32x4 o;
            o.x = e[r].x + f0 * w0.x + f1 * w1.x + f2 * w2.x + f3 * w3.x;
            o.y = e[r].y + f0 * w0.y + f1 * w1.y + f2 * w2.y + f3 * w3.y;
            o.z = e[r].z + f0 * w0.z + f1 * w1.z + f2 * w2.z + f3 * w3.z;
            o.w = e[r].w + f0 * w0.w + f1 * w1.w + f2 * w2.w + f3 * w3.w;
            __builtin_nontemporal_store(o, (f32x4*)(out + baseoff + (long long)r * DD));
        }
        idx0 = idx1; pv0 = pv1;
    }
}

// Generic fallback (any D multiple of 4): 1 row/wave.
__global__ __launch_bounds__(256) void posfeat_generic_kernel(
    const float* __restrict__ emb, const int* __restrict__ num,
    const float* __restrict__ pts, const int* __restrict__ indeces,
    const int* __restrict__ image_shape, const float* __restrict__ W,
    float* __restrict__ out, int B, int M, int N, int D)
{
    const int lane = threadIdx.x & 63;
    const int wave = threadIdx.x >> 6;
    const int m = blockIdx.x * 4 + wave;
    const int b = blockIdx.y;
    if (m >= M) return;
    const float h = (float)image_shape[2];
    const float w = (float)image_shape[3];
    const float inv_s = 1.0f / (fmaxf(w, h) * 0.7f);
    const float cx = w * 0.5f, cy = h * 0.5f;
    const float lscale = sqrtf(w * w + h * h) * 0.7f;
    const float inv_l = 1.0f / lscale;
    const float inv_a = 1.0f / 126.0f;
    float f0 = 0.f, f1 = 0.f, f2 = 0.f, f3 = 0.f;
    if (m < num[b]) {
        const int idx = indeces[(long long)b * M + m];
        const float* p = pts + ((long long)b * N + (long long)idx) * 5;
        f0 = (p[0] - cx) * inv_s;
        f1 = (p[1] - cy) * inv_s;
        f2 = (p[4] - 45.0f) * inv_a;
        f3 = (p[3] - lscale * 0.5f) * inv_l;
    }
    const long long rowoff = ((long long)b * M + m) * (long long)D;
    for (int dd = lane * 4; dd < D; dd += 64 * 4) {
        const f32x4 w0 = *(const f32x4*)(W + 0 * D + dd);
        const f32x4 w1 = *(const f32x4*)(W + 1 * D + dd);
        const f32x4 w2 = *(const f32x4*)(W + 2 * D + dd);
        const f32x4 w3 = *(const f32x4*)(W + 3 * D + dd);
        const f32x4 e  = *(const f32x4*)(emb + rowoff + dd);
        f32x4 r;
        r.x = e.x + f0 * w0.x + f1 * w1.x + f2 * w2.x + f3 * w3.x;
        r.y = e.y + f0 * w0.y + f1 * w1.y + f2 * w2.y + f3 * w3.y;
        r.z = e.z + f0 * w0.z + f1 * w1.z + f2 * w2.z + f3 * w3.z;
        r.w = e.w + f0 * w0.w + f1 * w1.w + f2 * w2.w + f3 * w3.w;
        *(f32x4*)(out + rowoff + dd) = r;
    }
}

extern "C" void kernel_launch(void* const* d_in, const int* in_sizes, int n_in,
                              void* d_out, int out_size, void* d_ws, size_t ws_size,
                              hipStream_t stream) {
    (void)n_in; (void)d_ws; (void)ws_size; (void)out_size;
    const float* emb  = (const float*)d_in[0];
    const int*   num  = (const int*)d_in[1];
    const float* pts  = (const float*)d_in[2];
    const int*   idx  = (const int*)d_in[3];
    const int*   ishp = (const int*)d_in[4];
    const float* Wm   = (const float*)d_in[5];
    float*       out  = (float*)d_out;

    const int B = in_sizes[1];
    const int D = in_sizes[5] / 4;
    const int M = (int)((long long)in_sizes[3] / B);
    const int N = (int)((long long)in_sizes[2] / ((long long)B * 5));

    if (D == 256 && (M % 8) == 0) {
        const int tiles_per_b = M / 8;
        // 2048 blocks total (8/CU x 256 CU): x = blocks per batch, y = batch
        int bx = 2048 / B; if (bx < 1) bx = 1;
        int waves_per_b = bx * 4;
        if (waves_per_b > tiles_per_b) bx = (tiles_per_b + 3) / 4;
        hipLaunchKernelGGL(posfeat_d256_kernel, dim3(bx, B), dim3(256), 0, stream,
                           emb, num, pts, idx, ishp, Wm, out, M, N, tiles_per_b);
    } else {
        dim3 block(256);
        dim3 grid((M + 3) / 4, B);
        hipLaunchKernelGGL(posfeat_generic_kernel, grid, block, 0, stream,
                           emb, num, pts, idx, ishp, Wm, out, B, M, N, D);
    }
}